// Round 14
// baseline (246.831 us; speedup 1.0000x reference)
//
#include <hip/hip_runtime.h>
#include <hip/hip_bf16.h>

#define NT 4096
#define HD 2048
#define NE 16
#define ID 512
#define TWO_I 1024
#define LP 266       // prep LDS row pitch in ushorts
#define MAXIT 31     // M=256 worklist: ceil(4081/256)=16 + 15 singletons

typedef __attribute__((ext_vector_type(8))) short bf16x8_t;
typedef __attribute__((ext_vector_type(4))) float f32x4_t;

__device__ __forceinline__ unsigned short f2bf(float f) {
  union { float f; unsigned int u; } v; v.f = f;
  unsigned int r = v.u + 0x7fffu + ((v.u >> 16) & 1u);
  return (unsigned short)(r >> 16);
}
__device__ __forceinline__ unsigned pk2(unsigned short a, unsigned short b) {
  return (unsigned)a | ((unsigned)b << 16);
}
// async global->LDS: LDS dest = wave-uniform base + lane*16; global src PER-LANE
__device__ __forceinline__ void gl_lds16(const void* g, void* l) {
  __builtin_amdgcn_global_load_lds(
      (const __attribute__((address_space(1))) unsigned int*)g,
      (__attribute__((address_space(3))) unsigned int*)l, 16, 0, 0);
}

// ============ weight prep: f32 [k][col] -> bf16 TRANSPOSED+SWIZZLED tiles =========
// layout: [e][cb][kt][64col x 64k tile]; elem (c,k) at c*64 + ((k>>3)^(c&7))*8 + (k&7)
__global__ __launch_bounds__(256) void k_prep_gu(const float* __restrict__ gup,
                                                 unsigned short* __restrict__ wgb) {
  int kt = blockIdx.x, e = blockIdx.y;           // grid (32, 16)
  int K0 = kt * 64;
  int t = threadIdx.x, w = t >> 6, lane = t & 63;
  __shared__ unsigned short L[64 * LP];
  int cgrp = t >> 3, m = t & 7;
  int kc = m ^ (cgrp & 7);
  for (int q = 0; q < 4; ++q) {
    for (int rd = 0; rd < 16; ++rd) {
      int row = rd * 4 + w;
      const float* s = gup + ((size_t)e * HD + K0 + row) * TWO_I + q * 256 + lane * 4;
      float4 v = *(const float4*)s;
      uint2 p; p.x = pk2(f2bf(v.x), f2bf(v.y)); p.y = pk2(f2bf(v.z), f2bf(v.w));
      *(uint2*)&L[row * LP + lane * 4] = p;
    }
    __syncthreads();
#pragma unroll
    for (int it = 0; it < 8; ++it) {
      int Cl = it * 32 + cgrp;
      int cb = q * 4 + (Cl >> 6), c = Cl & 63;
      const unsigned short* src = &L[(kc * 8) * LP + Cl];
      unsigned short tv[8];
#pragma unroll
      for (int j = 0; j < 8; ++j) tv[j] = src[j * LP];
      uint4 val;
      val.x = pk2(tv[0], tv[1]); val.y = pk2(tv[2], tv[3]);
      val.z = pk2(tv[4], tv[5]); val.w = pk2(tv[6], tv[7]);
      unsigned short* dst = wgb + (((size_t)e * 16 + cb) * 32 + kt) * 4096 + c * 64 + m * 8;
      *(uint4*)dst = val;
    }
    __syncthreads();
  }
}
__global__ __launch_bounds__(256) void k_prep_dn(const float* __restrict__ dwn,
                                                 unsigned short* __restrict__ wdb) {
  int kt = blockIdx.x, e = blockIdx.y, half = blockIdx.z;  // grid (8, 16, 2)
  int K0 = kt * 64;
  int t = threadIdx.x, w = t >> 6, lane = t & 63;
  __shared__ unsigned short L[64 * LP];
  int cgrp = t >> 3, m = t & 7;
  int kc = m ^ (cgrp & 7);
  for (int q = 0; q < 4; ++q) {
    for (int rd = 0; rd < 16; ++rd) {
      int row = rd * 4 + w;
      const float* s = dwn + ((size_t)e * ID + K0 + row) * HD + half * 1024 + q * 256 + lane * 4;
      float4 v = *(const float4*)s;
      uint2 p; p.x = pk2(f2bf(v.x), f2bf(v.y)); p.y = pk2(f2bf(v.z), f2bf(v.w));
      *(uint2*)&L[row * LP + lane * 4] = p;
    }
    __syncthreads();
#pragma unroll
    for (int it = 0; it < 8; ++it) {
      int Cl = it * 32 + cgrp;
      int cb = half * 16 + q * 4 + (Cl >> 6), c = Cl & 63;
      const unsigned short* src = &L[(kc * 8) * LP + Cl];
      unsigned short tv[8];
#pragma unroll
      for (int j = 0; j < 8; ++j) tv[j] = src[j * LP];
      uint4 val;
      val.x = pk2(tv[0], tv[1]); val.y = pk2(tv[2], tv[3]);
      val.z = pk2(tv[4], tv[5]); val.w = pk2(tv[6], tv[7]);
      unsigned short* dst = wdb + (((size_t)e * 32 + cb) * 8 + kt) * 4096 + c * 64 + m * 8;
      *(uint4*)dst = val;
    }
    __syncthreads();
  }
}

// ---------------- cast x (f32 -> bf16) ----------------
__global__ void k_cast_x(const float* __restrict__ x, unsigned short* __restrict__ xb) {
  size_t i = ((size_t)blockIdx.x * 256 + threadIdx.x) * 8;
  float4 a = *(const float4*)(x + i);
  float4 b = *(const float4*)(x + i + 4);
  uint4 pk;
  pk.x = pk2(f2bf(a.x), f2bf(a.y)); pk.y = pk2(f2bf(a.z), f2bf(a.w));
  pk.z = pk2(f2bf(b.x), f2bf(b.y)); pk.w = pk2(f2bf(b.z), f2bf(b.w));
  *(uint4*)(xb + i) = pk;
}

// ---------------- routing (+ fused histogram) ----------------
__global__ void k_route(const float* __restrict__ mu, const int* __restrict__ tok,
                        const float* __restrict__ wr, int* __restrict__ eid,
                        int* __restrict__ counts) {
  int t = blockIdx.x;
  int tid = threadIdx.x;
  float p[NE];
#pragma unroll
  for (int e = 0; e < NE; ++e) p[e] = 0.f;
  const float* m = mu + (size_t)t * HD;
  for (int h = tid; h < HD; h += 256) {
    float mv = m[h];
#pragma unroll
    for (int e = 0; e < NE; ++e) p[e] += mv * wr[e * HD + h];
  }
#pragma unroll
  for (int e = 0; e < NE; ++e) {
    float v = p[e];
#pragma unroll
    for (int s = 32; s; s >>= 1) v += __shfl_xor(v, s, 64);
    p[e] = v;
  }
  __shared__ float red[4][NE];
  int lane = tid & 63, wv = tid >> 6;
  if (lane == 0) {
#pragma unroll
    for (int e = 0; e < NE; ++e) red[wv][e] = p[e];
  }
  __syncthreads();
  if (tid == 0) {
    int tk = tok[t];
    if (tk < 0) tk = 0;
    if (tk > 31999) tk = 31999;
    int base = tk & 15;
    float best = -3.0e38f; int bi = 0;
    for (int e = 0; e < NE; ++e) {
      float v = red[0][e] + red[1][e] + red[2][e] + red[3][e];
      if (e == base) v += 10.0f;
      if (v > best) { best = v; bi = e; }
    }
    eid[t] = bi;
    atomicAdd(&counts[bi], 1);
  }
}

// ---------------- bucket tokens + worklist ----------------
__global__ void k_init(int* counts, int* cursors) {
  int i = threadIdx.x;
  if (i < NE) { counts[i] = 0; cursors[i] = 0; }
}
__global__ void k_scan(const int* __restrict__ counts, int* __restrict__ offsets,
                       int* __restrict__ cursors, int* __restrict__ wk) {
  if (threadIdx.x == 0) {
    int s = 0;
    for (int e = 0; e < NE; ++e) { offsets[e] = s; cursors[e] = s; s += counts[e]; }
    offsets[NE] = s;
    int n = 0;
    for (int e = 0; e < NE; ++e) {
      int tiles = (counts[e] + 255) >> 8;
      for (int m = 0; m < tiles; ++m) { wk[n++] = e | (m << 8); }
    }
    wk[MAXIT] = n;
  }
}
__global__ void k_scatter(const int* __restrict__ eid, int* __restrict__ cursors,
                          int* __restrict__ tlist) {
  int t = blockIdx.x * 256 + threadIdx.x;
  if (t < NT) {
    int e = eid[t];
    int pos = atomicAdd(&cursors[e], 1);
    tlist[pos] = t;
  }
}

// ---------------- gemm1: h = silu(x@Wg) * (x@Wu) ----------------
// 512 thr, M=256 x 64 h-cols; A+B in LDS, triple-buffered, counted vmcnt(12).
// Waves: wr=wv>>1 (64-row band), wc=wv&1 (32-col half of both gate & up).
__global__ __launch_bounds__(512, 2) void k_gemm1(
    const unsigned short* __restrict__ xb, const unsigned short* __restrict__ wgb,
    const int* __restrict__ offsets, const int* __restrict__ tlist,
    const int* __restrict__ wk, unsigned short* __restrict__ hbuf) {
  int item = blockIdx.y;
  if (item >= wk[MAXIT]) return;
  int w = wk[item];
  int e = w & 255, tb = (w >> 8) * 256;
  int off = offsets[e], cnt = offsets[e + 1] - off;
  int cx = blockIdx.x;
  int c0 = cx * 64;

  __shared__ unsigned short Ab[3][256 * 64];   // 96 KB, swizzled rows
  __shared__ unsigned short Bb[3][2][4096];    // 48 KB, pre-swizzled tiles
  __shared__ int ltok[256];

  int tid = threadIdx.x, lane = tid & 63, wv = tid >> 6;
  if (tid < 256) { int r = tb + tid; if (r > cnt - 1) r = cnt - 1; ltok[tid] = tlist[off + r]; }
  __syncthreads();

  int lr = lane & 15, hi = lane >> 4;
  int wr = wv >> 1, wc = wv & 1;

  // A staging: wave wv owns rows [wv*32, wv*32+32): 4 x 1KB gl_lds
  const unsigned short* aS[4];
  int aD[4];
  int cswz = (lane & 7) ^ ((lane >> 3) & 7);
#pragma unroll
  for (int i = 0; i < 4; ++i) {
    int row = wv * 32 + i * 8 + (lane >> 3);
    aS[i] = xb + (size_t)ltok[row] * HD + cswz * 8;
    aD[i] = (wv * 32 + i * 8) * 64;
  }
  // B staging: waves 0-3 -> gate tile, 4-7 -> up tile; 2 x 1KB each
  int bgu = wv >> 2, bpart = wv & 3;
  const unsigned short* bS =
      wgb + (((size_t)e * 16 + (bgu ? 8 + cx : cx)) * 32) * 4096 + bpart * 1024 + lane * 8;
  int bD = bpart * 1024;

#define STAGE(BUF) do { \
  _Pragma("unroll") for (int i = 0; i < 4; ++i) { gl_lds16(aS[i], &Ab[BUF][aD[i]]); aS[i] += 64; } \
  gl_lds16(bS, &Bb[BUF][bgu][bD]); gl_lds16(bS + 512, &Bb[BUF][bgu][bD + 512]); \
  bS += 4096; } while (0)

  f32x4_t zero = {0.f, 0.f, 0.f, 0.f};
  f32x4_t accg[4][2], accu[4][2];
#pragma unroll
  for (int m = 0; m < 4; ++m)
#pragma unroll
    for (int n = 0; n < 2; ++n) { accg[m][n] = zero; accu[m][n] = zero; }

#define SUBSTEP(KT, BUF, VMC) do { \
  asm volatile("s_waitcnt vmcnt(" #VMC ")" ::: "memory"); \
  __builtin_amdgcn_sched_barrier(0); \
  __builtin_amdgcn_s_barrier(); \
  bf16x8_t A_[2][4], Bg_[2][2], Bu_[2][2]; \
  _Pragma("unroll") for (int kk = 0; kk < 2; ++kk) { \
    int ch = kk * 4 + hi; \
    _Pragma("unroll") for (int m = 0; m < 4; ++m) { \
      int R = wr * 64 + m * 16 + lr; \
      A_[kk][m] = *(bf16x8_t*)&Ab[BUF][R * 64 + ((ch ^ (R & 7)) * 8)]; } \
    _Pragma("unroll") for (int n = 0; n < 2; ++n) { \
      int C = wc * 32 + n * 16 + lr; \
      int o = C * 64 + ((ch ^ (C & 7)) * 8); \
      Bg_[kk][n] = *(bf16x8_t*)&Bb[BUF][0][o]; \
      Bu_[kk][n] = *(bf16x8_t*)&Bb[BUF][1][o]; } } \
  asm volatile("s_waitcnt lgkmcnt(0)" ::: "memory"); \
  __builtin_amdgcn_sched_barrier(0); \
  __builtin_amdgcn_s_barrier(); \
  __builtin_amdgcn_s_setprio(1); \
  _Pragma("unroll") for (int kk = 0; kk < 2; ++kk) \
    _Pragma("unroll") for (int m = 0; m < 4; ++m) \
      _Pragma("unroll") for (int n = 0; n < 2; ++n) { \
        accg[m][n] = __builtin_amdgcn_mfma_f32_16x16x32_bf16(A_[kk][m], Bg_[kk][n], accg[m][n], 0, 0, 0); \
        accu[m][n] = __builtin_amdgcn_mfma_f32_16x16x32_bf16(A_[kk][m], Bu_[kk][n], accu[m][n], 0, 0, 0); } \
  __builtin_amdgcn_s_setprio(0); \
  if ((KT) + 3 < 32) STAGE(BUF); \
} while (0)

  STAGE(0); STAGE(1); STAGE(2);

  for (int g3 = 0; g3 < 10; ++g3) {
    SUBSTEP(g3 * 3 + 0, 0, 12);
    SUBSTEP(g3 * 3 + 1, 1, 12);
    SUBSTEP(g3 * 3 + 2, 2, 12);
  }
  SUBSTEP(30, 0, 6);
  SUBSTEP(31, 1, 0);

#undef SUBSTEP
#undef STAGE

  int rq = hi * 4;
#pragma unroll
  for (int m = 0; m < 4; ++m)
#pragma unroll
    for (int n = 0; n < 2; ++n)
#pragma unroll
      for (int j = 0; j < 4; ++j) {
        int r = tb + wr * 64 + m * 16 + rq + j;
        if (r < cnt) {
          float g = accg[m][n][j], u = accu[m][n][j];
          float hv = (g / (1.f + __expf(-g))) * u;
          hbuf[(size_t)(off + r) * ID + c0 + wc * 32 + n * 16 + lr] = f2bf(hv);
        }
      }
}

// ---------------- gemm2: out = h @ Wd ----------------
// 512 thr, M=256 x 128 out-cols (tiles 2cx, 2cx+1); wave wc owns one 64-col tile.
__global__ __launch_bounds__(512, 2) void k_gemm2(
    const unsigned short* __restrict__ hbuf, const unsigned short* __restrict__ wdb,
    const int* __restrict__ offsets, const int* __restrict__ tlist,
    const int* __restrict__ wk, float* __restrict__ out) {
  int item = blockIdx.y;
  if (item >= wk[MAXIT]) return;
  int w = wk[item];
  int e = w & 255, tb = (w >> 8) * 256;
  int off = offsets[e], cnt = offsets[e + 1] - off;
  int cx = blockIdx.x;
  int c0 = cx * 128;

  __shared__ unsigned short Ab[3][256 * 64];
  __shared__ unsigned short Bb[3][2][4096];

  int tid = threadIdx.x, lane = tid & 63, wv = tid >> 6;
  int lr = lane & 15, hi = lane >> 4;
  int wr = wv >> 1, wc = wv & 1;

  // A staging from hbuf (rows contiguous in expert order)
  const unsigned short* aS[4];
  int aD[4];
  int cswz = (lane & 7) ^ ((lane >> 3) & 7);
#pragma unroll
  for (int i = 0; i < 4; ++i) {
    int r = tb + wv * 32 + i * 8 + (lane >> 3);
    if (r > cnt - 1) r = cnt - 1;
    aS[i] = hbuf + (size_t)(off + r) * ID + cswz * 8;
    aD[i] = (wv * 32 + i * 8) * 64;
  }
  int bgu = wv >> 2, bpart = wv & 3;
  const unsigned short* bS =
      wdb + (((size_t)e * 32 + 2 * cx + bgu) * 8) * 4096 + bpart * 1024 + lane * 8;
  int bD = bpart * 1024;

#define STAGE(BUF) do { \
  _Pragma("unroll") for (int i = 0; i < 4; ++i) { gl_lds16(aS[i], &Ab[BUF][aD[i]]); aS[i] += 64; } \
  gl_lds16(bS, &Bb[BUF][bgu][bD]); gl_lds16(bS + 512, &Bb[BUF][bgu][bD + 512]); \
  bS += 4096; } while (0)

  f32x4_t zero = {0.f, 0.f, 0.f, 0.f};
  f32x4_t acc[4][4];
#pragma unroll
  for (int m = 0; m < 4; ++m)
#pragma unroll
    for (int n = 0; n < 4; ++n) acc[m][n] = zero;

#define SUBSTEP(KT, BUF, VMC) do { \
  asm volatile("s_waitcnt vmcnt(" #VMC ")" ::: "memory"); \
  __builtin_amdgcn_sched_barrier(0); \
  __builtin_amdgcn_s_barrier(); \
  bf16x8_t A_[2][4], B_[2][4]; \
  _Pragma("unroll") for (int kk = 0; kk < 2; ++kk) { \
    int ch = kk * 4 + hi; \
    _Pragma("unroll") for (int m = 0; m < 4; ++m) { \
      int R = wr * 64 + m * 16 + lr; \
      A_[kk][m] = *(bf16x8_t*)&Ab[BUF][R * 64 + ((ch ^ (R & 7)) * 8)]; } \
    _Pragma("unroll") for (int n = 0; n < 4; ++n) { \
      int C = n * 16 + lr; \
      B_[kk][n] = *(bf16x8_t*)&Bb[BUF][wc][C * 64 + ((ch ^ (C & 7)) * 8)]; } } \
  asm volatile("s_waitcnt lgkmcnt(0)" ::: "memory"); \
  __builtin_amdgcn_sched_barrier(0); \
  __builtin_amdgcn_s_barrier(); \
  __builtin_amdgcn_s_setprio(1); \
  _Pragma("unroll") for (int kk = 0; kk < 2; ++kk) \
    _Pragma("unroll") for (int m = 0; m < 4; ++m) \
      _Pragma("unroll") for (int n = 0; n < 4; ++n) \
        acc[m][n] = __builtin_amdgcn_mfma_f32_16x16x32_bf16(A_[kk][m], B_[kk][n], acc[m][n], 0, 0, 0); \
  __builtin_amdgcn_s_setprio(0); \
  if ((KT) + 3 < 8) STAGE(BUF); \
} while (0)

  STAGE(0); STAGE(1); STAGE(2);

  SUBSTEP(0, 0, 12);
  SUBSTEP(1, 1, 12);
  SUBSTEP(2, 2, 12);
  SUBSTEP(3, 0, 12);
  SUBSTEP(4, 1, 12);
  SUBSTEP(5, 2, 12);
  SUBSTEP(6, 0, 6);
  SUBSTEP(7, 1, 0);

#undef SUBSTEP
#undef STAGE

  int rq = hi * 4;
#pragma unroll
  for (int m = 0; m < 4; ++m)
#pragma unroll
    for (int n = 0; n < 4; ++n)
#pragma unroll
      for (int j = 0; j < 4; ++j) {
        int r = tb + wr * 64 + m * 16 + rq + j;
        if (r < cnt) {
          out[(size_t)tlist[off + r] * HD + c0 + wc * 64 + n * 16 + lr] = acc[m][n][j];
        }
      }
}

extern "C" void kernel_launch(void* const* d_in, const int* in_sizes, int n_in,
                              void* d_out, int out_size, void* d_ws, size_t ws_size,
                              hipStream_t stream) {
  (void)in_sizes; (void)n_in; (void)out_size; (void)ws_size;
  const float* x   = (const float*)d_in[0];
  const int*   tok = (const int*)d_in[1];
  const float* mu  = (const float*)d_in[2];
  const float* gup = (const float*)d_in[3];
  const float* dwn = (const float*)d_in[4];
  const float* wr  = (const float*)d_in[5];
  float* out = (float*)d_out;

  char* ws = (char*)d_ws;
  int* eid     = (int*)ws;
  int* tlist   = (int*)(ws + 16384);
  int* counts  = (int*)(ws + 32768);
  int* offsets = (int*)(ws + 32896);
  int* cursors = (int*)(ws + 33024);
  int* wk      = (int*)(ws + 33152);   // MAXIT+1 ints
  unsigned short* xb   = (unsigned short*)(ws + 65536);                       // 16 MB
  unsigned short* hbuf = (unsigned short*)(ws + 65536 + 16777216);            // 4 MB
  unsigned short* wgb  = (unsigned short*)(ws + 65536 + 16777216 + 4194304);  // 64 MB
  unsigned short* wdb  = (unsigned short*)(ws + 65536 + 16777216 + 4194304 + 67108864); // 32 MB

  k_prep_gu<<<dim3(32, 16), 256, 0, stream>>>(gup, wgb);
  k_prep_dn<<<dim3(8, 16, 2), 256, 0, stream>>>(dwn, wdb);
  k_cast_x <<<4096, 256, 0, stream>>>(x, xb);
  k_init   <<<1, 64, 0, stream>>>(counts, cursors);
  k_route  <<<NT, 256, 0, stream>>>(mu, tok, wr, eid, counts);
  k_scan   <<<1, 64, 0, stream>>>(counts, offsets, cursors, wk);
  k_scatter<<<16, 256, 0, stream>>>(eid, cursors, tlist);
  k_gemm1  <<<dim3(8, MAXIT), 512, 0, stream>>>(xb, wgb, offsets, tlist, wk, hbuf);
  k_gemm2  <<<dim3(16, MAXIT), 512, 0, stream>>>(hbuf, wdb, offsets, tlist, wk, out);
}